// Round 2
// baseline (1172.948 us; speedup 1.0000x reference)
//
#include <hip/hip_runtime.h>
#include <stdint.h>

#define T_TOK 1024
#define HID   2048
#define NE    8
#define INTER 5632
#define I2    11264
#define BK    64
#define RMAX  2560

typedef __bf16 bf16x8 __attribute__((ext_vector_type(8)));
typedef __bf16 bf16x4 __attribute__((ext_vector_type(4)));
typedef float  f32x4  __attribute__((ext_vector_type(4)));
typedef unsigned short u16;
typedef u16 u16x8 __attribute__((ext_vector_type(8)));

// meta layout (int view unless noted):
// [0..8)    counts[e]
// [8..16)   run[e]
// [24..32)  slotoff[e]
// [256..2304)  toke: {e0,e1} per token
// [2560..5120) rowtok[slot]
// float view:
// [5632..8192)  roww[slot]
// [8192..10240) tokw: {w0,w1} per token
// act buffer (bf16) at byte offset 65536: RMAX x INTER

// XOR-swizzled LDS byte offset: 128B rows, spread across 8 16B slots (T2)
__device__ __forceinline__ int swz(int row, int cb) {
    return row * 128 + (cb ^ ((row & 7) << 4));
}

__device__ __forceinline__ bf16x4 cvt4(float4 v) {
    bf16x4 r;
    r[0] = (__bf16)v.x; r[1] = (__bf16)v.y; r[2] = (__bf16)v.z; r[3] = (__bf16)v.w;
    return r;
}

__global__ void moe_router(const float* __restrict__ logits,
                           int* __restrict__ mi, float* __restrict__ mf) {
    int t = blockIdx.x * blockDim.x + threadIdx.x;
    if (t >= T_TOK) return;
    float l[NE];
#pragma unroll
    for (int i = 0; i < NE; ++i) l[i] = logits[t * NE + i];
    int e0 = 0; float v0 = l[0];
#pragma unroll
    for (int i = 1; i < NE; ++i) if (l[i] > v0) { v0 = l[i]; e0 = i; }
    int e1 = -1; float v1 = -3.4e38f;
#pragma unroll
    for (int i = 0; i < NE; ++i) if (i != e0 && l[i] > v1) { v1 = l[i]; e1 = i; }
    float ex = __expf(v1 - v0);          // <= 1
    float s  = 1.f + ex;
    float w0 = 1.f / s, w1 = ex / s;     // normalized top-2 softmax weights
    mi[256 + 2 * t]     = e0;
    mi[256 + 2 * t + 1] = e1;
    mf[8192 + 2 * t]     = w0;
    mf[8192 + 2 * t + 1] = w1;
    atomicAdd(&mi[e0], 1);
    atomicAdd(&mi[e1], 1);
}

__global__ void moe_plan(int* __restrict__ mi) {
    int tid = threadIdx.x;
    if (tid == 0) {
        int off = 0;
        for (int e = 0; e < NE; ++e) {
            mi[24 + e] = off;                       // slotoff
            off += ((mi[e] + 63) >> 6) << 6;        // 64-padded
            mi[8 + e] = 0;                          // run
        }
    }
    for (int i = tid; i < RMAX; i += blockDim.x) mi[2560 + i] = -1;
}

__global__ void moe_scatter(int* __restrict__ mi, float* __restrict__ mf) {
    int t = blockIdx.x * blockDim.x + threadIdx.x;
    if (t >= T_TOK) return;
    int e0 = mi[256 + 2 * t], e1 = mi[256 + 2 * t + 1];
    float w0 = mf[8192 + 2 * t], w1 = mf[8192 + 2 * t + 1];
    int p0 = atomicAdd(&mi[8 + e0], 1);
    int s0 = mi[24 + e0] + p0;
    mi[2560 + s0] = t; mf[5632 + s0] = w0;
    int p1 = atomicAdd(&mi[8 + e1], 1);
    int s1 = mi[24 + e1] + p1;
    mi[2560 + s1] = t; mf[5632 + s1] = w1;
}

// ---------------- GEMM1: act[slot,i] = silu(XW_g^T)*(XW_u^T) ----------------
// grid (INTER/128, NE, 2); block loops row-tiles rt = z, z+2, ... of expert e.
// Weight strip (128 rows gate + 128 up) read cold ~once; LDS XOR-swizzled;
// k+1 loads issued before MFMA phase (2-phase pipeline).

#define G1_LOAD(K0)                                                          \
    _Pragma("unroll")                                                        \
    for (int it = 0; it < 4; ++it) {                                         \
        int r = sr + it * 16;                                                \
        int tok = toks[r];                                                   \
        ra[it] = (tok >= 0)                                                  \
            ? *(const float4*)(hidden + (size_t)tok * HID + (K0) + sc)       \
            : make_float4(0.f, 0.f, 0.f, 0.f);                               \
    }                                                                        \
    _Pragma("unroll")                                                        \
    for (int it = 0; it < 8; ++it) {                                         \
        int r = sr + it * 16;                                                \
        rg[it] = *(const float4*)(bg_base + (size_t)r * HID + (K0) + sc);    \
        ru[it] = *(const float4*)(bu_base + (size_t)r * HID + (K0) + sc);    \
    }

#define G1_WRITE()                                                           \
    _Pragma("unroll")                                                        \
    for (int it = 0; it < 4; ++it)                                           \
        *(bf16x4*)((char*)As + swz(sr + it * 16, scb)) = cvt4(ra[it]);       \
    _Pragma("unroll")                                                        \
    for (int it = 0; it < 8; ++it) {                                         \
        *(bf16x4*)((char*)Bgs + swz(sr + it * 16, scb)) = cvt4(rg[it]);      \
        *(bf16x4*)((char*)Bus + swz(sr + it * 16, scb)) = cvt4(ru[it]);      \
    }

#define G1_MFMA()                                                            \
    _Pragma("unroll")                                                        \
    for (int kk = 0; kk < 2; ++kk) {                                         \
        int kb = kk * 64 + lk * 16;                                          \
        bf16x8 a0 = *(const bf16x8*)((const char*)As + swz(wm * 32 + lrow, kb));      \
        bf16x8 a1 = *(const bf16x8*)((const char*)As + swz(wm * 32 + 16 + lrow, kb)); \
        _Pragma("unroll")                                                    \
        for (int fn = 0; fn < 4; ++fn) {                                     \
            bf16x8 bg = *(const bf16x8*)((const char*)Bgs + swz(wn * 64 + fn * 16 + lrow, kb)); \
            bf16x8 bu = *(const bf16x8*)((const char*)Bus + swz(wn * 64 + fn * 16 + lrow, kb)); \
            accg[0][fn] = __builtin_amdgcn_mfma_f32_16x16x32_bf16(a0, bg, accg[0][fn], 0, 0, 0); \
            accg[1][fn] = __builtin_amdgcn_mfma_f32_16x16x32_bf16(a1, bg, accg[1][fn], 0, 0, 0); \
            accu[0][fn] = __builtin_amdgcn_mfma_f32_16x16x32_bf16(a0, bu, accu[0][fn], 0, 0, 0); \
            accu[1][fn] = __builtin_amdgcn_mfma_f32_16x16x32_bf16(a1, bu, accu[1][fn], 0, 0, 0); \
        }                                                                    \
    }

__global__ __launch_bounds__(256) void moe_gemm1(
        const float* __restrict__ hidden, const float* __restrict__ w13,
        const int* __restrict__ mi, u16* __restrict__ act) {
    const int ct = blockIdx.x;
    const int e  = blockIdx.y;
    const int zr = blockIdx.z;
    const int ntiles = (mi[e] + 63) >> 6;
    const int slot0  = mi[24 + e];
    const int* rowtok = mi + 2560;

    __shared__ __align__(16) u16 As[64 * 64];
    __shared__ __align__(16) u16 Bgs[128 * 64];
    __shared__ __align__(16) u16 Bus[128 * 64];
    __shared__ int toks[64];

    const int tid = threadIdx.x;
    const int w = tid >> 6, lane = tid & 63;
    const int wm = w >> 1, wn = w & 1;
    const int lrow = lane & 15, lk = lane >> 4;

    const int sr  = tid >> 4;          // staging row group
    const int sc  = (tid & 15) * 4;    // f32 col
    const int scb = (tid & 15) * 8;    // bf16 byte col

    const float* bg_base = w13 + ((size_t)e * I2 + (size_t)ct * 128) * HID;
    const float* bu_base = bg_base + (size_t)INTER * HID;

    for (int rt = zr; rt < ntiles; rt += 2) {
        const int row_base = slot0 + rt * 64;
        if (tid < 64) toks[tid] = rowtok[row_base + tid];
        __syncthreads();

        f32x4 accg[2][4] = {}, accu[2][4] = {};
        float4 ra[4], rg[8], ru[8];

        G1_LOAD(0)
        G1_WRITE()
        __syncthreads();
        for (int k0 = BK; k0 <= HID; k0 += BK) {
            const bool more = k0 < HID;
            if (more) { G1_LOAD(k0) }
            G1_MFMA()
            __syncthreads();
            if (more) { G1_WRITE() __syncthreads(); }
        }

        const size_t actbase = (size_t)row_base * INTER + (size_t)ct * 128;
#pragma unroll
        for (int fm = 0; fm < 2; ++fm)
#pragma unroll
        for (int fn = 0; fn < 4; ++fn)
#pragma unroll
        for (int j = 0; j < 4; ++j) {
            int row = wm * 32 + fm * 16 + lk * 4 + j;
            int col = wn * 64 + fn * 16 + lrow;
            float g = accg[fm][fn][j], u = accu[fm][fn][j];
            float a = g / (1.f + __expf(-g)) * u;
            ((__bf16*)act)[actbase + (size_t)row * INTER + col] = (__bf16)a;
        }
    }
}

// ---------------- GEMM2: out[tok,:] += roww * act[slot,:] @ W2^T ------------
// grid (HID/64, NE); block loops all row-tiles of expert e. BN=64.

#define G2_LOAD(K0)                                                          \
    _Pragma("unroll")                                                        \
    for (int it = 0; it < 2; ++it) {                                         \
        int r = (tid >> 3) + it * 32;                                        \
        raa[it] = *(const u16x8*)(act + (size_t)(row_base + r) * INTER + (K0) + ac); \
    }                                                                        \
    _Pragma("unroll")                                                        \
    for (int it = 0; it < 4; ++it) {                                         \
        int r = sr + it * 16;                                                \
        rb[it] = *(const float4*)(b_base + (size_t)r * INTER + (K0) + sc);   \
    }

#define G2_WRITE()                                                           \
    _Pragma("unroll")                                                        \
    for (int it = 0; it < 2; ++it)                                           \
        *(u16x8*)((char*)As2 + swz((tid >> 3) + it * 32, acb)) = raa[it];    \
    _Pragma("unroll")                                                        \
    for (int it = 0; it < 4; ++it)                                           \
        *(bf16x4*)((char*)Bs2 + swz(sr + it * 16, scb)) = cvt4(rb[it]);

#define G2_MFMA()                                                            \
    _Pragma("unroll")                                                        \
    for (int kk = 0; kk < 2; ++kk) {                                         \
        int kb = kk * 64 + lk * 16;                                          \
        bf16x8 a0 = *(const bf16x8*)((const char*)As2 + swz(wm * 32 + lrow, kb));      \
        bf16x8 a1 = *(const bf16x8*)((const char*)As2 + swz(wm * 32 + 16 + lrow, kb)); \
        _Pragma("unroll")                                                    \
        for (int fn = 0; fn < 2; ++fn) {                                     \
            bf16x8 b = *(const bf16x8*)((const char*)Bs2 + swz(wn * 32 + fn * 16 + lrow, kb)); \
            acc[0][fn] = __builtin_amdgcn_mfma_f32_16x16x32_bf16(a0, b, acc[0][fn], 0, 0, 0); \
            acc[1][fn] = __builtin_amdgcn_mfma_f32_16x16x32_bf16(a1, b, acc[1][fn], 0, 0, 0); \
        }                                                                    \
    }

__global__ __launch_bounds__(256) void moe_gemm2(
        const u16* __restrict__ act, const float* __restrict__ w2,
        const int* __restrict__ mi, const float* __restrict__ mf,
        float* __restrict__ out) {
    const int ct = blockIdx.x;   // 0..31
    const int e  = blockIdx.y;
    const int ntiles = (mi[e] + 63) >> 6;
    const int slot0  = mi[24 + e];
    const int* rowtok = mi + 2560;
    const float* roww = mf + 5632;

    __shared__ __align__(16) u16 As2[64 * 64];
    __shared__ __align__(16) u16 Bs2[64 * 64];

    const int tid = threadIdx.x;
    const int w = tid >> 6, lane = tid & 63;
    const int wm = w >> 1, wn = w & 1;
    const int lrow = lane & 15, lk = lane >> 4;

    const int sr  = tid >> 4;
    const int sc  = (tid & 15) * 4;
    const int scb = (tid & 15) * 8;
    const int ac  = (tid & 7) * 8;     // act u16 col
    const int acb = (tid & 7) * 16;    // act byte col

    const float* b_base = w2 + ((size_t)e * HID + (size_t)ct * 64) * INTER;

    for (int rt = 0; rt < ntiles; ++rt) {
        const int row_base = slot0 + rt * 64;
        f32x4 acc[2][2] = {};
        u16x8 raa[2]; float4 rb[4];

        G2_LOAD(0)
        __syncthreads();   // prior rt's MFMA reads done before overwrite
        G2_WRITE()
        __syncthreads();
        for (int k0 = BK; k0 <= INTER; k0 += BK) {
            const bool more = k0 < INTER;
            if (more) { G2_LOAD(k0) }
            G2_MFMA()
            __syncthreads();
            if (more) { G2_WRITE() __syncthreads(); }
        }

#pragma unroll
        for (int fm = 0; fm < 2; ++fm)
#pragma unroll
        for (int fn = 0; fn < 2; ++fn)
#pragma unroll
        for (int j = 0; j < 4; ++j) {
            int row = wm * 32 + fm * 16 + lk * 4 + j;
            int col = wn * 32 + fn * 16 + lrow;
            int slot = row_base + row;
            int tok = rowtok[slot];
            if (tok >= 0)
                atomicAdd(out + (size_t)tok * HID + (size_t)ct * 64 + col,
                          acc[fm][fn][j] * roww[slot]);
        }
    }
}

extern "C" void kernel_launch(void* const* d_in, const int* in_sizes, int n_in,
                              void* d_out, int out_size, void* d_ws, size_t ws_size,
                              hipStream_t stream) {
    const float* hidden = (const float*)d_in[0];
    const float* logits = (const float*)d_in[1];
    const float* w13    = (const float*)d_in[2];
    const float* w2     = (const float*)d_in[3];
    float* out = (float*)d_out;

    int*   mi  = (int*)d_ws;
    float* mf  = (float*)d_ws;
    u16*   act = (u16*)((char*)d_ws + 65536);

    hipMemsetAsync(d_ws, 0, 64, stream);
    hipMemsetAsync(d_out, 0, (size_t)out_size * sizeof(float), stream);

    moe_router<<<dim3(T_TOK / 256), 256, 0, stream>>>(logits, mi, mf);
    moe_plan<<<dim3(1), 256, 0, stream>>>(mi);
    moe_scatter<<<dim3(T_TOK / 256), 256, 0, stream>>>(mi, mf);
    moe_gemm1<<<dim3(INTER / 128, NE, 2), 256, 0, stream>>>(hidden, w13, mi, act);
    moe_gemm2<<<dim3(HID / 64, NE), 256, 0, stream>>>(act, w2, mi, mf, out);
}

// Round 3
// 797.519 us; speedup vs baseline: 1.4707x; 1.4707x over previous
//
#include <hip/hip_runtime.h>
#include <stdint.h>

#define T_TOK 1024
#define HID   2048
#define NE    8
#define INTER 5632
#define I2    11264
#define BK    64
#define MAXTILES 40
#define RMAX  2560
#define KCH   1408   // INTER/4, GEMM2 K-split chunk

typedef __bf16 bf16x8 __attribute__((ext_vector_type(8)));
typedef __bf16 bf16x4 __attribute__((ext_vector_type(4)));
typedef float  f32x4  __attribute__((ext_vector_type(4)));
typedef unsigned short u16;
typedef u16 u16x8 __attribute__((ext_vector_type(8)));

// meta layout (int view unless noted):
// [0..8) counts[e]  [8..16) run[e]  [16] ntiles  [24..32) slotoff[e]
// [32..112) tiles {e,row_base}  [256..2304) toke  [2560..5120) rowtok
// float view: [5632..8192) roww   [8192..10240) tokw
// act (bf16) at byte 65536: RMAX x INTER

__device__ __forceinline__ int swz(int row, int cb) {
    return row * 128 + (cb ^ ((row & 7) << 4));
}

__device__ __forceinline__ bf16x4 cvt4(float4 v) {
    bf16x4 r;
    r[0] = (__bf16)v.x; r[1] = (__bf16)v.y; r[2] = (__bf16)v.z; r[3] = (__bf16)v.w;
    return r;
}

__global__ void moe_router(const float* __restrict__ logits,
                           int* __restrict__ mi, float* __restrict__ mf) {
    int t = blockIdx.x * blockDim.x + threadIdx.x;
    if (t >= T_TOK) return;
    float l[NE];
#pragma unroll
    for (int i = 0; i < NE; ++i) l[i] = logits[t * NE + i];
    int e0 = 0; float v0 = l[0];
#pragma unroll
    for (int i = 1; i < NE; ++i) if (l[i] > v0) { v0 = l[i]; e0 = i; }
    int e1 = -1; float v1 = -3.4e38f;
#pragma unroll
    for (int i = 0; i < NE; ++i) if (i != e0 && l[i] > v1) { v1 = l[i]; e1 = i; }
    float ex = __expf(v1 - v0);
    float s  = 1.f + ex;
    mi[256 + 2 * t]     = e0;
    mi[256 + 2 * t + 1] = e1;
    mf[8192 + 2 * t]     = 1.f / s;
    mf[8192 + 2 * t + 1] = ex / s;
    atomicAdd(&mi[e0], 1);
    atomicAdd(&mi[e1], 1);
}

__global__ void moe_plan(int* __restrict__ mi) {
    int tid = threadIdx.x;
    if (tid == 0) {
        int off = 0, nt = 0;
        for (int e = 0; e < NE; ++e) {
            int c = mi[e];
            mi[24 + e] = off;
            int ntile = (c + 63) >> 6;
            for (int j = 0; j < ntile; ++j) {
                mi[32 + 2 * nt]     = e;
                mi[32 + 2 * nt + 1] = off + j * 64;
                ++nt;
            }
            off += ntile * 64;
            mi[8 + e] = 0;
        }
        mi[16] = nt;
    }
    for (int i = tid; i < RMAX; i += blockDim.x) mi[2560 + i] = -1;
}

__global__ void moe_scatter(int* __restrict__ mi, float* __restrict__ mf) {
    int t = blockIdx.x * blockDim.x + threadIdx.x;
    if (t >= T_TOK) return;
    int e0 = mi[256 + 2 * t], e1 = mi[256 + 2 * t + 1];
    float w0 = mf[8192 + 2 * t], w1 = mf[8192 + 2 * t + 1];
    int p0 = atomicAdd(&mi[8 + e0], 1);
    int s0 = mi[24 + e0] + p0;
    mi[2560 + s0] = t; mf[5632 + s0] = w0;
    int p1 = atomicAdd(&mi[8 + e1], 1);
    int s1 = mi[24 + e1] + p1;
    mi[2560 + s1] = t; mf[5632 + s1] = w1;
}

// ---------------- GEMM1: one 64x128 tile per block, 2-phase pipeline --------

#define G1_LOAD(K0)                                                          \
    _Pragma("unroll")                                                        \
    for (int it = 0; it < 4; ++it)                                           \
        ra[it] = aptr[it] ? *(const float4*)(aptr[it] + (K0))                \
                          : make_float4(0.f, 0.f, 0.f, 0.f);                 \
    _Pragma("unroll")                                                        \
    for (int it = 0; it < 8; ++it) {                                         \
        rg[it] = *(const float4*)(bgp[it] + (K0));                           \
        ru[it] = *(const float4*)(bup[it] + (K0));                           \
    }

#define G1_WRITE()                                                           \
    _Pragma("unroll")                                                        \
    for (int it = 0; it < 4; ++it)                                           \
        *(bf16x4*)((char*)As + swz(sr + it * 16, scb)) = cvt4(ra[it]);       \
    _Pragma("unroll")                                                        \
    for (int it = 0; it < 8; ++it) {                                         \
        *(bf16x4*)((char*)Bgs + swz(sr + it * 16, scb)) = cvt4(rg[it]);      \
        *(bf16x4*)((char*)Bus + swz(sr + it * 16, scb)) = cvt4(ru[it]);      \
    }

#define G1_MFMA()                                                            \
    _Pragma("unroll")                                                        \
    for (int kk = 0; kk < 2; ++kk) {                                         \
        int kb = kk * 64 + lk * 16;                                          \
        bf16x8 a0 = *(const bf16x8*)((const char*)As + swz(wm * 32 + lrow, kb));      \
        bf16x8 a1 = *(const bf16x8*)((const char*)As + swz(wm * 32 + 16 + lrow, kb)); \
        _Pragma("unroll")                                                    \
        for (int fn = 0; fn < 4; ++fn) {                                     \
            bf16x8 bg = *(const bf16x8*)((const char*)Bgs + swz(wn * 64 + fn * 16 + lrow, kb)); \
            bf16x8 bu = *(const bf16x8*)((const char*)Bus + swz(wn * 64 + fn * 16 + lrow, kb)); \
            accg[0][fn] = __builtin_amdgcn_mfma_f32_16x16x32_bf16(a0, bg, accg[0][fn], 0, 0, 0); \
            accg[1][fn] = __builtin_amdgcn_mfma_f32_16x16x32_bf16(a1, bg, accg[1][fn], 0, 0, 0); \
            accu[0][fn] = __builtin_amdgcn_mfma_f32_16x16x32_bf16(a0, bu, accu[0][fn], 0, 0, 0); \
            accu[1][fn] = __builtin_amdgcn_mfma_f32_16x16x32_bf16(a1, bu, accu[1][fn], 0, 0, 0); \
        }                                                                    \
    }

__global__ __launch_bounds__(256) void moe_gemm1(
        const float* __restrict__ hidden, const float* __restrict__ w13,
        const int* __restrict__ mi, u16* __restrict__ act) {
    const int tj = blockIdx.x, ct = blockIdx.y;
    if (tj >= mi[16]) return;
    const int e = mi[32 + 2 * tj], row_base = mi[32 + 2 * tj + 1];
    const int* rowtok = mi + 2560;

    __shared__ __align__(16) u16 As[64 * 64];
    __shared__ __align__(16) u16 Bgs[128 * 64];
    __shared__ __align__(16) u16 Bus[128 * 64];
    __shared__ int toks[64];

    const int tid = threadIdx.x;
    const int w = tid >> 6, lane = tid & 63;
    const int wm = w >> 1, wn = w & 1;
    const int lrow = lane & 15, lk = lane >> 4;

    const int sr  = tid >> 4;
    const int sc  = (tid & 15) * 4;
    const int scb = (tid & 15) * 8;

    if (tid < 64) toks[tid] = rowtok[row_base + tid];
    __syncthreads();

    // per-thread row pointers (const across K)
    const float* aptr[4];
#pragma unroll
    for (int it = 0; it < 4; ++it) {
        int tok = toks[sr + it * 16];
        aptr[it] = (tok >= 0) ? hidden + (size_t)tok * HID + sc : nullptr;
    }
    const float* bg_base = w13 + ((size_t)e * I2 + (size_t)ct * 128) * HID;
    const float* bu_base = bg_base + (size_t)INTER * HID;
    const float* bgp[8];
    const float* bup[8];
#pragma unroll
    for (int it = 0; it < 8; ++it) {
        bgp[it] = bg_base + (size_t)(sr + it * 16) * HID + sc;
        bup[it] = bu_base + (size_t)(sr + it * 16) * HID + sc;
    }

    f32x4 accg[2][4] = {}, accu[2][4] = {};
    float4 ra[4], rg[8], ru[8];

    G1_LOAD(0)
    G1_WRITE()
    __syncthreads();
    for (int k0 = BK; k0 <= HID; k0 += BK) {
        const bool more = k0 < HID;
        if (more) { G1_LOAD(k0) }
        G1_MFMA()
        __syncthreads();
        if (more) { G1_WRITE() __syncthreads(); }
    }

    const size_t actbase = (size_t)row_base * INTER + (size_t)ct * 128;
#pragma unroll
    for (int fm = 0; fm < 2; ++fm)
#pragma unroll
    for (int fn = 0; fn < 4; ++fn)
#pragma unroll
    for (int j = 0; j < 4; ++j) {
        int row = wm * 32 + fm * 16 + lk * 4 + j;
        int col = wn * 64 + fn * 16 + lrow;
        float g = accg[fm][fn][j], u = accu[fm][fn][j];
        float a = g / (1.f + __expf(-g)) * u;
        ((__bf16*)act)[actbase + (size_t)row * INTER + col] = (__bf16)a;
    }
}

// ------- GEMM2: one 64x64 tile per (tile, ct, kz) block; K-split z=4 --------

#define G2_LOAD(K0)                                                          \
    _Pragma("unroll")                                                        \
    for (int it = 0; it < 2; ++it)                                           \
        raa[it] = *(const u16x8*)(ap2[it] + (K0));                           \
    _Pragma("unroll")                                                        \
    for (int it = 0; it < 4; ++it)                                           \
        rb[it] = *(const float4*)(bp2[it] + (K0));

#define G2_WRITE()                                                           \
    _Pragma("unroll")                                                        \
    for (int it = 0; it < 2; ++it)                                           \
        *(u16x8*)((char*)As2 + swz((tid >> 3) + it * 32, acb)) = raa[it];    \
    _Pragma("unroll")                                                        \
    for (int it = 0; it < 4; ++it)                                           \
        *(bf16x4*)((char*)Bs2 + swz(sr + it * 16, scb)) = cvt4(rb[it]);

#define G2_MFMA()                                                            \
    _Pragma("unroll")                                                        \
    for (int kk = 0; kk < 2; ++kk) {                                         \
        int kb = kk * 64 + lk * 16;                                          \
        bf16x8 a0 = *(const bf16x8*)((const char*)As2 + swz(wm * 32 + lrow, kb));      \
        bf16x8 a1 = *(const bf16x8*)((const char*)As2 + swz(wm * 32 + 16 + lrow, kb)); \
        _Pragma("unroll")                                                    \
        for (int fn = 0; fn < 2; ++fn) {                                     \
            bf16x8 b = *(const bf16x8*)((const char*)Bs2 + swz(wn * 32 + fn * 16 + lrow, kb)); \
            acc[0][fn] = __builtin_amdgcn_mfma_f32_16x16x32_bf16(a0, b, acc[0][fn], 0, 0, 0); \
            acc[1][fn] = __builtin_amdgcn_mfma_f32_16x16x32_bf16(a1, b, acc[1][fn], 0, 0, 0); \
        }                                                                    \
    }

__global__ __launch_bounds__(256) void moe_gemm2(
        const u16* __restrict__ act, const float* __restrict__ w2,
        const int* __restrict__ mi, const float* __restrict__ mf,
        float* __restrict__ out) {
    const int tj = blockIdx.x, ct = blockIdx.y, kz = blockIdx.z;
    if (tj >= mi[16]) return;
    const int e = mi[32 + 2 * tj], row_base = mi[32 + 2 * tj + 1];
    const int* rowtok = mi + 2560;
    const float* roww = mf + 5632;

    __shared__ __align__(16) u16 As2[64 * 64];
    __shared__ __align__(16) u16 Bs2[64 * 64];

    const int tid = threadIdx.x;
    const int w = tid >> 6, lane = tid & 63;
    const int wm = w >> 1, wn = w & 1;
    const int lrow = lane & 15, lk = lane >> 4;

    const int sr  = tid >> 4;
    const int sc  = (tid & 15) * 4;
    const int scb = (tid & 15) * 8;
    const int ac  = (tid & 7) * 8;
    const int acb = (tid & 7) * 16;

    const u16* ap2[2];
#pragma unroll
    for (int it = 0; it < 2; ++it)
        ap2[it] = act + (size_t)(row_base + (tid >> 3) + it * 32) * INTER + ac;
    const float* b_base = w2 + ((size_t)e * HID + (size_t)ct * 64) * INTER;
    const float* bp2[4];
#pragma unroll
    for (int it = 0; it < 4; ++it)
        bp2[it] = b_base + (size_t)(sr + it * 16) * INTER + sc;

    const int kbeg = kz * KCH, kend = kbeg + KCH;

    f32x4 acc[2][2] = {};
    u16x8 raa[2]; float4 rb[4];

    G2_LOAD(kbeg)
    G2_WRITE()
    __syncthreads();
    for (int k0 = kbeg + BK; k0 <= kend; k0 += BK) {
        const bool more = k0 < kend;
        if (more) { G2_LOAD(k0) }
        G2_MFMA()
        __syncthreads();
        if (more) { G2_WRITE() __syncthreads(); }
    }

#pragma unroll
    for (int fm = 0; fm < 2; ++fm)
#pragma unroll
    for (int fn = 0; fn < 2; ++fn)
#pragma unroll
    for (int j = 0; j < 4; ++j) {
        int row = wm * 32 + fm * 16 + lk * 4 + j;
        int col = wn * 32 + fn * 16 + lrow;
        int slot = row_base + row;
        int tok = rowtok[slot];
        if (tok >= 0)
            atomicAdd(out + (size_t)tok * HID + (size_t)ct * 64 + col,
                      acc[fm][fn][j] * roww[slot]);
    }
}

extern "C" void kernel_launch(void* const* d_in, const int* in_sizes, int n_in,
                              void* d_out, int out_size, void* d_ws, size_t ws_size,
                              hipStream_t stream) {
    const float* hidden = (const float*)d_in[0];
    const float* logits = (const float*)d_in[1];
    const float* w13    = (const float*)d_in[2];
    const float* w2     = (const float*)d_in[3];
    float* out = (float*)d_out;

    int*   mi  = (int*)d_ws;
    float* mf  = (float*)d_ws;
    u16*   act = (u16*)((char*)d_ws + 65536);

    hipMemsetAsync(d_ws, 0, 64, stream);
    hipMemsetAsync(d_out, 0, (size_t)out_size * sizeof(float), stream);

    moe_router<<<dim3(T_TOK / 256), 256, 0, stream>>>(logits, mi, mf);
    moe_plan<<<dim3(1), 256, 0, stream>>>(mi);
    moe_scatter<<<dim3(T_TOK / 256), 256, 0, stream>>>(mi, mf);
    moe_gemm1<<<dim3(MAXTILES, INTER / 128), 256, 0, stream>>>(hidden, w13, mi, act);
    moe_gemm2<<<dim3(MAXTILES, HID / 64, INTER / KCH), 256, 0, stream>>>(act, w2, mi, mf, out);
}

// Round 4
// 578.251 us; speedup vs baseline: 2.0284x; 1.3792x over previous
//
#include <hip/hip_runtime.h>
#include <stdint.h>

#define T_TOK 1024
#define HID   2048
#define NE    8
#define INTER 5632
#define I2    11264
#define BK    64
#define MAXT  20     // sum ceil(c64/128) <= 2048/128 + 4
#define RMAX  2560
#define KCH   1408   // INTER/4, GEMM2 K-split chunk

typedef __bf16 bf16x8 __attribute__((ext_vector_type(8)));
typedef __bf16 bf16x4 __attribute__((ext_vector_type(4)));
typedef float  f32x4  __attribute__((ext_vector_type(4)));
typedef unsigned short u16;
typedef u16 u16x8 __attribute__((ext_vector_type(8)));

// meta layout (int view unless noted):
// [0..8) counts[e]  [8..16) run[e]  [16] ntiles  [24..32) slotoff[e]
// [32..112) tiles {e,row_base}  [256..2304) toke  [2560..5120) rowtok
// float view: [5632..8192) roww   [8192..10240) tokw
// act (bf16) at byte 65536: RMAX x INTER

__device__ __forceinline__ int swz(int row, int cb) {
    return row * 128 + (cb ^ ((row & 7) << 4));
}

__device__ __forceinline__ bf16x4 cvt4(float4 v) {
    bf16x4 r;
    r[0] = (__bf16)v.x; r[1] = (__bf16)v.y; r[2] = (__bf16)v.z; r[3] = (__bf16)v.w;
    return r;
}

__global__ void moe_router(const float* __restrict__ logits,
                           int* __restrict__ mi, float* __restrict__ mf) {
    int t = blockIdx.x * blockDim.x + threadIdx.x;
    if (t >= T_TOK) return;
    float l[NE];
#pragma unroll
    for (int i = 0; i < NE; ++i) l[i] = logits[t * NE + i];
    int e0 = 0; float v0 = l[0];
#pragma unroll
    for (int i = 1; i < NE; ++i) if (l[i] > v0) { v0 = l[i]; e0 = i; }
    int e1 = -1; float v1 = -3.4e38f;
#pragma unroll
    for (int i = 0; i < NE; ++i) if (i != e0 && l[i] > v1) { v1 = l[i]; e1 = i; }
    float ex = __expf(v1 - v0);
    float s  = 1.f + ex;
    mi[256 + 2 * t]     = e0;
    mi[256 + 2 * t + 1] = e1;
    mf[8192 + 2 * t]     = 1.f / s;
    mf[8192 + 2 * t + 1] = ex / s;
    atomicAdd(&mi[e0], 1);
    atomicAdd(&mi[e1], 1);
}

__global__ void moe_plan(int* __restrict__ mi) {
    int tid = threadIdx.x;
    if (tid == 0) {
        int off = 0, nt = 0;
        for (int e = 0; e < NE; ++e) {
            int c = mi[e];
            mi[24 + e] = off;
            int c64 = ((c + 63) >> 6) << 6;
            int ntile = (c64 + 127) >> 7;          // 128-row tiles over 64-padded region
            for (int j = 0; j < ntile; ++j) {
                mi[32 + 2 * nt]     = e;
                mi[32 + 2 * nt + 1] = off + j * 128;
                ++nt;
            }
            off += c64;
            mi[8 + e] = 0;
        }
        mi[16] = nt;
    }
    for (int i = tid; i < RMAX; i += blockDim.x) mi[2560 + i] = -1;
}

__global__ void moe_scatter(int* __restrict__ mi, float* __restrict__ mf) {
    int t = blockIdx.x * blockDim.x + threadIdx.x;
    if (t >= T_TOK) return;
    int e0 = mi[256 + 2 * t], e1 = mi[256 + 2 * t + 1];
    float w0 = mf[8192 + 2 * t], w1 = mf[8192 + 2 * t + 1];
    int p0 = atomicAdd(&mi[8 + e0], 1);
    int s0 = mi[24 + e0] + p0;
    mi[2560 + s0] = t; mf[5632 + s0] = w0;
    int p1 = atomicAdd(&mi[8 + e1], 1);
    int s1 = mi[24 + e1] + p1;
    mi[2560 + s1] = t; mf[5632 + s1] = w1;
}

// -------- GEMM1: 128x64 tile (gate+up) per block, 2-phase pipeline ----------

#define G1_LOAD(K0)                                                          \
    _Pragma("unroll")                                                        \
    for (int it = 0; it < 8; ++it)                                           \
        ra[it] = aptr[it] ? *(const float4*)(aptr[it] + (K0))                \
                          : make_float4(0.f, 0.f, 0.f, 0.f);                 \
    _Pragma("unroll")                                                        \
    for (int it = 0; it < 4; ++it) {                                         \
        rg[it] = *(const float4*)(bgp[it] + (K0));                           \
        ru[it] = *(const float4*)(bup[it] + (K0));                           \
    }

#define G1_WRITE()                                                           \
    _Pragma("unroll")                                                        \
    for (int it = 0; it < 8; ++it)                                           \
        *(bf16x4*)((char*)As + swz(sr + it * 16, scb)) = cvt4(ra[it]);       \
    _Pragma("unroll")                                                        \
    for (int it = 0; it < 4; ++it) {                                         \
        *(bf16x4*)((char*)Bgs + swz(sr + it * 16, scb)) = cvt4(rg[it]);      \
        *(bf16x4*)((char*)Bus + swz(sr + it * 16, scb)) = cvt4(ru[it]);      \
    }

#define G1_MFMA()                                                            \
    _Pragma("unroll")                                                        \
    for (int kk = 0; kk < 2; ++kk) {                                         \
        int kb = kk * 64 + lk * 16;                                          \
        bf16x8 a0 = *(const bf16x8*)((const char*)As + swz(wm * 32 + lrow, kb));      \
        bf16x8 a1 = *(const bf16x8*)((const char*)As + swz(wm * 32 + 16 + lrow, kb)); \
        _Pragma("unroll")                                                    \
        for (int fn = 0; fn < 4; ++fn) {                                     \
            bf16x8 bg = *(const bf16x8*)((const char*)Bgs + swz(fn * 16 + lrow, kb)); \
            bf16x8 bu = *(const bf16x8*)((const char*)Bus + swz(fn * 16 + lrow, kb)); \
            accg[0][fn] = __builtin_amdgcn_mfma_f32_16x16x32_bf16(a0, bg, accg[0][fn], 0, 0, 0); \
            accg[1][fn] = __builtin_amdgcn_mfma_f32_16x16x32_bf16(a1, bg, accg[1][fn], 0, 0, 0); \
            accu[0][fn] = __builtin_amdgcn_mfma_f32_16x16x32_bf16(a0, bu, accu[0][fn], 0, 0, 0); \
            accu[1][fn] = __builtin_amdgcn_mfma_f32_16x16x32_bf16(a1, bu, accu[1][fn], 0, 0, 0); \
        }                                                                    \
    }

__global__ __launch_bounds__(256) void moe_gemm1(
        const float* __restrict__ hidden, const float* __restrict__ w13,
        const int* __restrict__ mi, u16* __restrict__ act) {
    const int tj = blockIdx.x, ct = blockIdx.y;   // ct in 0..87
    if (tj >= mi[16]) return;
    const int e = mi[32 + 2 * tj], row_base = mi[32 + 2 * tj + 1];
    const int* rowtok = mi + 2560;
    const int limit = mi[24 + e] + (((mi[e] + 63) >> 6) << 6);

    __shared__ __align__(16) u16 As[128 * 64];
    __shared__ __align__(16) u16 Bgs[64 * 64];
    __shared__ __align__(16) u16 Bus[64 * 64];
    __shared__ int toks[128];

    const int tid = threadIdx.x;
    const int w = tid >> 6, lane = tid & 63;
    const int wm = w;
    const int lrow = lane & 15, lk = lane >> 4;

    const int sr  = tid >> 4;          // 0..15
    const int sc  = (tid & 15) * 4;
    const int scb = (tid & 15) * 8;

    if (tid < 128) {
        int idx = row_base + tid;
        toks[tid] = (idx < limit) ? rowtok[idx] : -1;
    }
    __syncthreads();

    const float* aptr[8];
#pragma unroll
    for (int it = 0; it < 8; ++it) {
        int tok = toks[sr + it * 16];
        aptr[it] = (tok >= 0) ? hidden + (size_t)tok * HID + sc : nullptr;
    }
    const float* bg_base = w13 + ((size_t)e * I2 + (size_t)ct * 64) * HID;
    const float* bu_base = bg_base + (size_t)INTER * HID;
    const float* bgp[4];
    const float* bup[4];
#pragma unroll
    for (int it = 0; it < 4; ++it) {
        bgp[it] = bg_base + (size_t)(sr + it * 16) * HID + sc;
        bup[it] = bu_base + (size_t)(sr + it * 16) * HID + sc;
    }

    f32x4 accg[2][4] = {}, accu[2][4] = {};
    float4 ra[8], rg[4], ru[4];

    G1_LOAD(0)
    G1_WRITE()
    __syncthreads();
    for (int k0 = BK; k0 <= HID; k0 += BK) {
        const bool more = k0 < HID;
        if (more) { G1_LOAD(k0) }
        G1_MFMA()
        __syncthreads();
        if (more) { G1_WRITE() __syncthreads(); }
    }

    const size_t actbase = (size_t)row_base * INTER + (size_t)ct * 64;
#pragma unroll
    for (int fm = 0; fm < 2; ++fm)
#pragma unroll
    for (int fn = 0; fn < 4; ++fn)
#pragma unroll
    for (int j = 0; j < 4; ++j) {
        int row = wm * 32 + fm * 16 + lk * 4 + j;
        int col = fn * 16 + lrow;
        if (toks[row] >= 0) {
            float g = accg[fm][fn][j], u = accu[fm][fn][j];
            float a = g / (1.f + __expf(-g)) * u;
            ((__bf16*)act)[actbase + (size_t)row * INTER + col] = (__bf16)a;
        }
    }
}

// -------- GEMM2: 128x64 tile per (tile, ct, kz) block; K-split z=4 ----------

#define G2_LOAD(K0)                                                          \
    _Pragma("unroll")                                                        \
    for (int it = 0; it < 4; ++it)                                           \
        raa[it] = *(const u16x8*)(ap2[it] + (K0));                           \
    _Pragma("unroll")                                                        \
    for (int it = 0; it < 4; ++it)                                           \
        rb[it] = *(const float4*)(bp2[it] + (K0));

#define G2_WRITE()                                                           \
    _Pragma("unroll")                                                        \
    for (int it = 0; it < 4; ++it)                                           \
        *(u16x8*)((char*)As2 + swz((tid >> 3) + it * 32, acb)) = raa[it];    \
    _Pragma("unroll")                                                        \
    for (int it = 0; it < 4; ++it)                                           \
        *(bf16x4*)((char*)Bs2 + swz(sr + it * 16, scb)) = cvt4(rb[it]);

#define G2_MFMA()                                                            \
    _Pragma("unroll")                                                        \
    for (int kk = 0; kk < 2; ++kk) {                                         \
        int kb = kk * 64 + lk * 16;                                          \
        bf16x8 a0 = *(const bf16x8*)((const char*)As2 + swz(wm * 32 + lrow, kb));      \
        bf16x8 a1 = *(const bf16x8*)((const char*)As2 + swz(wm * 32 + 16 + lrow, kb)); \
        _Pragma("unroll")                                                    \
        for (int fn = 0; fn < 4; ++fn) {                                     \
            bf16x8 b = *(const bf16x8*)((const char*)Bs2 + swz(fn * 16 + lrow, kb)); \
            acc[0][fn] = __builtin_amdgcn_mfma_f32_16x16x32_bf16(a0, b, acc[0][fn], 0, 0, 0); \
            acc[1][fn] = __builtin_amdgcn_mfma_f32_16x16x32_bf16(a1, b, acc[1][fn], 0, 0, 0); \
        }                                                                    \
    }

__global__ __launch_bounds__(256) void moe_gemm2(
        const u16* __restrict__ act, const float* __restrict__ w2,
        const int* __restrict__ mi, const float* __restrict__ mf,
        float* __restrict__ out) {
    const int tj = blockIdx.x, ct = blockIdx.y, kz = blockIdx.z;  // ct 0..31
    if (tj >= mi[16]) return;
    const int e = mi[32 + 2 * tj], row_base = mi[32 + 2 * tj + 1];
    const int* rowtok = mi + 2560;
    const float* roww = mf + 5632;
    const int limit = mi[24 + e] + (((mi[e] + 63) >> 6) << 6);

    __shared__ __align__(16) u16 As2[128 * 64];
    __shared__ __align__(16) u16 Bs2[64 * 64];

    const int tid = threadIdx.x;
    const int w = tid >> 6, lane = tid & 63;
    const int wm = w;
    const int lrow = lane & 15, lk = lane >> 4;

    const int sr  = tid >> 4;
    const int sc  = (tid & 15) * 4;
    const int scb = (tid & 15) * 8;
    const int ac  = (tid & 7) * 8;
    const int acb = (tid & 7) * 16;

    const u16* ap2[4];
#pragma unroll
    for (int it = 0; it < 4; ++it) {
        int r = row_base + (tid >> 3) + it * 32;
        if (r > RMAX - 1) r = RMAX - 1;            // clamp: garbage rows discarded per-row
        ap2[it] = act + (size_t)r * INTER + ac;
    }
    const float* b_base = w2 + ((size_t)e * HID + (size_t)ct * 64) * INTER;
    const float* bp2[4];
#pragma unroll
    for (int it = 0; it < 4; ++it)
        bp2[it] = b_base + (size_t)(sr + it * 16) * INTER + sc;

    const int kbeg = kz * KCH, kend = kbeg + KCH;

    f32x4 acc[2][4] = {};
    u16x8 raa[4]; float4 rb[4];

    G2_LOAD(kbeg)
    G2_WRITE()
    __syncthreads();
    for (int k0 = kbeg + BK; k0 <= kend; k0 += BK) {
        const bool more = k0 < kend;
        if (more) { G2_LOAD(k0) }
        G2_MFMA()
        __syncthreads();
        if (more) { G2_WRITE() __syncthreads(); }
    }

#pragma unroll
    for (int fm = 0; fm < 2; ++fm)
#pragma unroll
    for (int fn = 0; fn < 4; ++fn)
#pragma unroll
    for (int j = 0; j < 4; ++j) {
        int row = wm * 32 + fm * 16 + lk * 4 + j;
        int col = fn * 16 + lrow;
        int slot = row_base + row;
        if (slot < limit) {
            int tok = rowtok[slot];
            if (tok >= 0)
                atomicAdd(out + (size_t)tok * HID + (size_t)ct * 64 + col,
                          acc[fm][fn][j] * roww[slot]);
        }
    }
}

extern "C" void kernel_launch(void* const* d_in, const int* in_sizes, int n_in,
                              void* d_out, int out_size, void* d_ws, size_t ws_size,
                              hipStream_t stream) {
    const float* hidden = (const float*)d_in[0];
    const float* logits = (const float*)d_in[1];
    const float* w13    = (const float*)d_in[2];
    const float* w2     = (const float*)d_in[3];
    float* out = (float*)d_out;

    int*   mi  = (int*)d_ws;
    float* mf  = (float*)d_ws;
    u16*   act = (u16*)((char*)d_ws + 65536);

    hipMemsetAsync(d_ws, 0, 64, stream);
    hipMemsetAsync(d_out, 0, (size_t)out_size * sizeof(float), stream);

    moe_router<<<dim3(T_TOK / 256), 256, 0, stream>>>(logits, mi, mf);
    moe_plan<<<dim3(1), 256, 0, stream>>>(mi);
    moe_scatter<<<dim3(T_TOK / 256), 256, 0, stream>>>(mi, mf);
    moe_gemm1<<<dim3(MAXT, INTER / 64), 256, 0, stream>>>(hidden, w13, mi, act);
    moe_gemm2<<<dim3(MAXT, HID / 64, INTER / KCH), 256, 0, stream>>>(act, w2, mi, mf, out);
}